// Round 2
// baseline (542.773 us; speedup 1.0000x reference)
//
#include <hip/hip_runtime.h>
#include <hip/hip_fp16.h>
#include <hip/hip_cooperative_groups.h>
#include <stdint.h>

namespace cg = cooperative_groups;

typedef _Float16 half_t;
typedef __attribute__((ext_vector_type(8))) _Float16 half8;   // MFMA A/B frag (4 VGPRs)
typedef __attribute__((ext_vector_type(16))) float f32x16;    // 32x32 MFMA C/D frag
typedef __attribute__((ext_vector_type(4)))  float float4v;

#define BM 128
#define BN 128
#define BK 64   // 8 chunks of 8 halves (16 B) per row

__device__ __forceinline__ void gld_lds16(const void* g, void* l) {
    __builtin_amdgcn_global_load_lds(
        (const __attribute__((address_space(1))) void*)g,
        (__attribute__((address_space(3))) void*)l, 16, 0, 0);
}

// ---------------------------------------------------------------------------
// ONE cooperative dispatch: phase 1 quantizes x,w (fp32 -> f16 RNE == the
// reference e5m10 quantize) into d_ws; grid.sync() (+device fences for
// cross-XCD L2 visibility); phase 2 is the proven 128x128 global_load_lds
// GEMM reading the f16 panels. d_ws is fully rewritten inside EVERY dispatch
// => no cross-call state (the R0 two-kernel post-timing failure class).
//
// GEMM: C[m][n] = sum_k qA[m][k]*qB[n][k] + q(bias[n]); 4 waves (2x2 of
// 64x64), mfma_f32_32x32x16_f16, XOR chunk swizzle on LDS k-chunks, XCD-aware
// block swizzle (4-wide bn strip per XCD).
// Co-residency: 1024 blocks x 256 thr, 32KB LDS, VGPR<=128 via
// __launch_bounds__(256,4) => 4 blocks/CU x 256 CU = 1024.  [perf-only]
// ---------------------------------------------------------------------------
__global__ __launch_bounds__(256, 4)
void gemm_coop(const float* __restrict__ x, const float* __restrict__ w,
               const float* __restrict__ bias, float* __restrict__ C,
               half_t* __restrict__ q, int M, int N, int K) {
    // ---------------- phase 1: quantize both tensors into q ----------------
    const long na   = (long)M * K;
    const long ntot = na + (long)N * K;
    {
        const long nchunk = ntot >> 3;
        const long nthr   = (long)gridDim.x * blockDim.x;
        long cid = (long)blockIdx.x * blockDim.x + threadIdx.x;
        for (long c = cid; c < nchunk; c += nthr) {
            const long i = c * 8;
            if (i < na && i + 8 > na) {           // straddle guard (generic)
                for (long j = i; j < i + 8; ++j)
                    q[j] = (half_t)(j < na ? x[j] : w[j - na]);
                continue;
            }
            const float* src = (i < na) ? (x + i) : (w + (i - na));
            float4v v0 = *(const float4v*)(src);
            float4v v1 = *(const float4v*)(src + 4);
            half8 h;
            h[0] = (half_t)v0[0]; h[1] = (half_t)v0[1];
            h[2] = (half_t)v0[2]; h[3] = (half_t)v0[3];
            h[4] = (half_t)v1[0]; h[5] = (half_t)v1[1];
            h[6] = (half_t)v1[2]; h[7] = (half_t)v1[3];
            *(half8*)(q + i) = h;
        }
        if (cid == 0)
            for (long i = nchunk * 8; i < ntot; ++i)
                q[i] = (half_t)(i < na ? x[i] : w[i - na]);
    }

    __threadfence();          // agent-scope release: push q out of this XCD's L2
    cg::this_grid().sync();
    __threadfence();          // agent-scope acquire: drop any stale lines

    // ---------------- phase 2: GEMM on f16 panels --------------------------
    const half_t* A = q;           // [M][K]
    const half_t* B = q + na;      // [N][K]

    __shared__ half_t sA[BM * BK];   // 16 KB
    __shared__ half_t sB[BN * BK];   // 16 KB

    const int t    = threadIdx.x;
    const int lane = t & 63;
    const int wave = t >> 6;
    const int wm   = (wave >> 1) * 64;
    const int wn   = (wave & 1) * 64;

    // XCD-aware 1-D -> 2-D block swizzle (specialized for the 32x32 grid)
    const int nbx = N / BN, nby = M / BM;
    int bxi, byi;
    {
        const int b = blockIdx.x;
        if (nbx == 32 && nby == 32) {
            const int xcd = b & 7;
            const int s   = b >> 3;
            bxi = xcd * 4 + (s & 3);   // bn strip of 4 per XCD
            byi = s >> 2;
        } else {
            bxi = b % nbx;
            byi = b / nbx;
        }
    }
    const int bm = byi * BM;
    const int bn = bxi * BN;

    // staging: 1024 16B-chunks per matrix, 4 per thread; chunk index c:
    // row = c>>3, LDS pos = c&7, global k-chunk = (c&7) ^ (row&7)
    int srow[4], skc[4];
    #pragma unroll
    for (int s = 0; s < 4; ++s) {
        const int c = t + 256 * s;
        srow[s] = c >> 3;
        skc[s]  = (c & 7) ^ (srow[s] & 7);
    }

    f32x16 acc[2][2] = {};

    const int ml = lane & 31;   // m (or n) within 32-tile
    const int kg = lane >> 5;   // which 8-k half of the MFMA's K=16
    const int sw = ml & 7;      // row component of the XOR swizzle

    for (int k0 = 0; k0 < K; k0 += BK) {
        #pragma unroll
        for (int s = 0; s < 4; ++s) {
            const long ga = (long)(bm + srow[s]) * K + k0 + skc[s] * 8;
            const long gb = (long)(bn + srow[s]) * K + k0 + skc[s] * 8;
            gld_lds16(A + ga, &sA[(t + 256 * s) * 8]);
            gld_lds16(B + gb, &sB[(t + 256 * s) * 8]);
        }
        __syncthreads();   // compiler emits vmcnt(0) before s_barrier

        #pragma unroll
        for (int ks = 0; ks < 4; ++ks) {
            const int cp = 2 * ks + kg;                    // k-chunk 0..7
            const int pa0 = ((wm      + ml) * 8 + (cp ^ sw)) * 8;
            const int pa1 = ((wm + 32 + ml) * 8 + (cp ^ sw)) * 8;
            const int pb0 = ((wn      + ml) * 8 + (cp ^ sw)) * 8;
            const int pb1 = ((wn + 32 + ml) * 8 + (cp ^ sw)) * 8;
            half8 a0 = *(const half8*)&sA[pa0];
            half8 a1 = *(const half8*)&sA[pa1];
            half8 b0 = *(const half8*)&sB[pb0];
            half8 b1 = *(const half8*)&sB[pb1];
            acc[0][0] = __builtin_amdgcn_mfma_f32_32x32x16_f16(a0, b0, acc[0][0], 0, 0, 0);
            acc[0][1] = __builtin_amdgcn_mfma_f32_32x32x16_f16(a0, b1, acc[0][1], 0, 0, 0);
            acc[1][0] = __builtin_amdgcn_mfma_f32_32x32x16_f16(a1, b0, acc[1][0], 0, 0, 0);
            acc[1][1] = __builtin_amdgcn_mfma_f32_32x32x16_f16(a1, b1, acc[1][1], 0, 0, 0);
        }
        __syncthreads();
    }

    // Epilogue. 32x32 C/D layout [m74/m101]: col = lane&31,
    // row = (reg&3) + 8*(reg>>2) + 4*(lane>>5)
    const int cl = lane & 31;
    const int rb = 4 * (lane >> 5);
    #pragma unroll
    for (int j = 0; j < 2; ++j) {
        const int col = bn + wn + j * 32 + cl;
        const float bq = (float)(half_t)bias[col];   // inline bias quantize
        #pragma unroll
        for (int i = 0; i < 2; ++i) {
            #pragma unroll
            for (int r = 0; r < 16; ++r) {
                const int row = bm + wm + i * 32 + (r & 3) + 8 * (r >> 2) + rb;
                C[(long)row * N + col] = acc[i][j][r] + bq;
            }
        }
    }
}

// ---------------------------------------------------------------------------
// Fallback: fully fused quantize-on-stage GEMM (verified R1, 403 us). Used
// only if ws_size is insufficient or cooperative launch is rejected.
// ---------------------------------------------------------------------------
__global__ __launch_bounds__(256)
void gemm_qf16_fused(const float* __restrict__ A, const float* __restrict__ B,
                     const float* __restrict__ bias, float* __restrict__ C,
                     int M, int N, int K) {
    __shared__ half_t sA[BM * BK];
    __shared__ half_t sB[BN * BK];

    const int t    = threadIdx.x;
    const int lane = t & 63;
    const int wave = t >> 6;
    const int wm   = (wave >> 1) * 64;
    const int wn   = (wave & 1) * 64;

    const int nbx = N / BN, nby = M / BM;
    int bxi, byi;
    {
        const int b = blockIdx.x;
        if (nbx == 32 && nby == 32) {
            const int xcd = b & 7;
            const int s   = b >> 3;
            bxi = xcd * 4 + (s & 3);
            byi = s >> 2;
        } else {
            bxi = b % nbx;
            byi = b / nbx;
        }
    }
    const int bm = byi * BM;
    const int bn = bxi * BN;

    int srow[4], skc[4];
    #pragma unroll
    for (int s = 0; s < 4; ++s) {
        const int c = t + 256 * s;
        srow[s] = c >> 3;
        skc[s]  = (c & 7) ^ (srow[s] & 7);
    }

    f32x16 acc[2][2] = {};

    const int ml = lane & 31;
    const int kg = lane >> 5;
    const int sw = ml & 7;

    for (int k0 = 0; k0 < K; k0 += BK) {
        #pragma unroll
        for (int s = 0; s < 4; ++s) {
            const long ga = (long)(bm + srow[s]) * K + k0 + skc[s] * 8;
            const long gb = (long)(bn + srow[s]) * K + k0 + skc[s] * 8;
            float4v a0 = *(const float4v*)(A + ga);
            float4v a1 = *(const float4v*)(A + ga + 4);
            float4v b0 = *(const float4v*)(B + gb);
            float4v b1 = *(const float4v*)(B + gb + 4);
            half8 ha, hb;
            ha[0]=(half_t)a0[0]; ha[1]=(half_t)a0[1]; ha[2]=(half_t)a0[2]; ha[3]=(half_t)a0[3];
            ha[4]=(half_t)a1[0]; ha[5]=(half_t)a1[1]; ha[6]=(half_t)a1[2]; ha[7]=(half_t)a1[3];
            hb[0]=(half_t)b0[0]; hb[1]=(half_t)b0[1]; hb[2]=(half_t)b0[2]; hb[3]=(half_t)b0[3];
            hb[4]=(half_t)b1[0]; hb[5]=(half_t)b1[1]; hb[6]=(half_t)b1[2]; hb[7]=(half_t)b1[3];
            *(half8*)&sA[(t + 256 * s) * 8] = ha;
            *(half8*)&sB[(t + 256 * s) * 8] = hb;
        }
        __syncthreads();

        #pragma unroll
        for (int ks = 0; ks < 4; ++ks) {
            const int cp = 2 * ks + kg;
            const int pa0 = ((wm      + ml) * 8 + (cp ^ sw)) * 8;
            const int pa1 = ((wm + 32 + ml) * 8 + (cp ^ sw)) * 8;
            const int pb0 = ((wn      + ml) * 8 + (cp ^ sw)) * 8;
            const int pb1 = ((wn + 32 + ml) * 8 + (cp ^ sw)) * 8;
            half8 a0 = *(const half8*)&sA[pa0];
            half8 a1 = *(const half8*)&sA[pa1];
            half8 b0 = *(const half8*)&sB[pb0];
            half8 b1 = *(const half8*)&sB[pb1];
            acc[0][0] = __builtin_amdgcn_mfma_f32_32x32x16_f16(a0, b0, acc[0][0], 0, 0, 0);
            acc[0][1] = __builtin_amdgcn_mfma_f32_32x32x16_f16(a0, b1, acc[0][1], 0, 0, 0);
            acc[1][0] = __builtin_amdgcn_mfma_f32_32x32x16_f16(a1, b0, acc[1][0], 0, 0, 0);
            acc[1][1] = __builtin_amdgcn_mfma_f32_32x32x16_f16(a1, b1, acc[1][1], 0, 0, 0);
        }
        __syncthreads();
    }

    const int cl = lane & 31;
    const int rb = 4 * (lane >> 5);
    #pragma unroll
    for (int j = 0; j < 2; ++j) {
        const int col = bn + wn + j * 32 + cl;
        const float bq = (float)(half_t)bias[col];
        #pragma unroll
        for (int i = 0; i < 2; ++i) {
            #pragma unroll
            for (int r = 0; r < 16; ++r) {
                const int row = bm + wm + i * 32 + (r & 3) + 8 * (r >> 2) + rb;
                C[(long)row * N + col] = acc[i][j][r] + bq;
            }
        }
    }
}

extern "C" void kernel_launch(void* const* d_in, const int* in_sizes, int n_in,
                              void* d_out, int out_size, void* d_ws, size_t ws_size,
                              hipStream_t stream) {
    const float* x    = (const float*)d_in[0];
    const float* w    = (const float*)d_in[1];
    const float* bias = (const float*)d_in[2];
    float* out = (float*)d_out;

    const int OUT = in_sizes[2];
    const int IN  = in_sizes[1] / OUT;
    const int M   = in_sizes[0] / IN;
    const int N   = OUT, K = IN;

    const int nblk = (N / BN) * (M / BM);
    const size_t needed = ((size_t)M * K + (size_t)N * K) * sizeof(half_t);

    if (ws_size >= needed) {
        half_t* q = (half_t*)d_ws;
        void* args[] = {(void*)&x, (void*)&w, (void*)&bias, (void*)&out,
                        (void*)&q, (void*)&M, (void*)&N, (void*)&K};
        hipError_t e = hipLaunchCooperativeKernel((const void*)gemm_coop,
                                                  dim3(nblk), dim3(256),
                                                  args, 0, stream);
        if (e == hipSuccess) return;
        // cooperative rejected -> fall through to the verified fused kernel
    }
    gemm_qf16_fused<<<nblk, 256, 0, stream>>>(x, w, bias, out, M, N, K);
    (void)n_in; (void)out_size;
}

// Round 3
// 350.146 us; speedup vs baseline: 1.5501x; 1.5501x over previous
//
#include <hip/hip_runtime.h>
#include <hip/hip_fp16.h>
#include <stdint.h>

typedef _Float16 half_t;
typedef __attribute__((ext_vector_type(8))) _Float16 half8;   // MFMA A/B frag (4 VGPRs)
typedef __attribute__((ext_vector_type(16))) float f32x16;    // 32x32 MFMA C/D frag
typedef __attribute__((ext_vector_type(4)))  float float4v;

#define BM 128
#define BN 128
#define BK 64   // 8 chunks of 8 halves (16 B) per row

// ---------------------------------------------------------------------------
// Single fused kernel (stateless, no d_ws, no second dispatch — R0's
// post-timing failure class eliminated; R2's coop detour regressed 437us).
//
// R3 change vs the 304us R1 kernel: double-buffered LDS + async-STAGE split
// (T14). Old K-step was fully serial:
//   load fp32 -> wait -> cvt -> ds_write -> barrier -> MFMA -> barrier
// New K-step (ONE barrier per step):
//   issue loads(t+1) -> MFMA over lds[cur] -> vmcnt wait -> cvt ->
//   ds_write lds[cur^1] -> barrier
// Loads for t+1 are in flight across the whole MFMA phase of t, so the
// global-load latency (the dominant serial term per R1 counters: MfmaUtil
// 19%, VALUBusy 9.5%, HBM 17%, all idle) is hidden.
// Buffer hazard audit: iter t reads buf[cur], writes buf[cur^1]; all reads
// of buf[cur^1] finished at iter t-1 whose trailing barrier separates them;
// trailing barrier of t publishes the writes for t+1. Correct with one
// barrier per iteration.
//
// quantize == fp32->f16 RNE cvt (reference e5m10 quantize incl. denormals),
// applied on stage for A/B and inline for bias.
// GEMM: C[m][n] = sum_k qA[m][k]*qB[n][k] + q(bias[n]); 4 waves (2x2 of
// 64x64), mfma_f32_32x32x16_f16, XOR chunk swizzle on LDS k-chunks,
// XCD-aware block swizzle (4-wide bn strip per XCD, perf-only).
// ---------------------------------------------------------------------------
__global__ __launch_bounds__(256)
void gemm_qf16_dbuf(const float* __restrict__ A, const float* __restrict__ B,
                    const float* __restrict__ bias, float* __restrict__ C,
                    int M, int N, int K) {
    __shared__ half_t sA[2][BM * BK];   // 2 x 16 KB
    __shared__ half_t sB[2][BN * BK];   // 2 x 16 KB

    const int t    = threadIdx.x;
    const int lane = t & 63;
    const int wave = t >> 6;
    const int wm   = (wave >> 1) * 64;
    const int wn   = (wave & 1) * 64;

    // XCD-aware 1-D -> 2-D block swizzle (specialized for the 32x32 grid)
    const int nbx = N / BN, nby = M / BM;
    int bxi, byi;
    {
        const int b = blockIdx.x;
        if (nbx == 32 && nby == 32) {
            const int xcd = b & 7;
            const int s   = b >> 3;
            bxi = xcd * 4 + (s & 3);   // bn strip of 4 per XCD
            byi = s >> 2;
        } else {
            bxi = b % nbx;
            byi = b / nbx;
        }
    }
    const int bm = byi * BM;
    const int bn = bxi * BN;

    // staging: 1024 16B-f16-chunks per matrix per K-step, 4 per thread;
    // chunk c: row = c>>3, LDS pos = c&7, global k-chunk = (c&7) ^ (row&7)
    // Per-s global pointers, advanced by BK each K-step (saves VALU addr math).
    const float* pa[4];
    const float* pb[4];
    int ldsoff[4];
    #pragma unroll
    for (int s = 0; s < 4; ++s) {
        const int c   = t + 256 * s;
        const int row = c >> 3;
        const int kc  = (c & 7) ^ (row & 7);
        pa[s] = A + (long)(bm + row) * K + kc * 8;
        pb[s] = B + (long)(bn + row) * K + kc * 8;
        ldsoff[s] = c * 8;
    }

    f32x16 acc[2][2] = {};

    const int ml = lane & 31;   // m (or n) within 32-tile
    const int kg = lane >> 5;   // which 8-k half of the MFMA's K=16
    const int sw = ml & 7;      // row component of the XOR swizzle

    // in-flight staging registers (constant-indexed via full unroll)
    float4v ra0[4], ra1[4], rb0[4], rb1[4];

    const int NT = K / BK;

    // ---- prologue: load + cvt + write buf 0 ----
    #pragma unroll
    for (int s = 0; s < 4; ++s) {
        ra0[s] = *(const float4v*)(pa[s]);
        ra1[s] = *(const float4v*)(pa[s] + 4);
        rb0[s] = *(const float4v*)(pb[s]);
        rb1[s] = *(const float4v*)(pb[s] + 4);
        pa[s] += BK; pb[s] += BK;
    }
    #pragma unroll
    for (int s = 0; s < 4; ++s) {
        half8 ha, hb;
        ha[0]=(half_t)ra0[s][0]; ha[1]=(half_t)ra0[s][1]; ha[2]=(half_t)ra0[s][2]; ha[3]=(half_t)ra0[s][3];
        ha[4]=(half_t)ra1[s][0]; ha[5]=(half_t)ra1[s][1]; ha[6]=(half_t)ra1[s][2]; ha[7]=(half_t)ra1[s][3];
        hb[0]=(half_t)rb0[s][0]; hb[1]=(half_t)rb0[s][1]; hb[2]=(half_t)rb0[s][2]; hb[3]=(half_t)rb0[s][3];
        hb[4]=(half_t)rb1[s][0]; hb[5]=(half_t)rb1[s][1]; hb[6]=(half_t)rb1[s][2]; hb[7]=(half_t)rb1[s][3];
        *(half8*)&sA[0][ldsoff[s]] = ha;
        *(half8*)&sB[0][ldsoff[s]] = hb;
    }
    __syncthreads();

    int cur = 0;
    for (int kt = 0; kt < NT; ++kt) {
        const bool more = (kt + 1 < NT);

        // ---- issue next tile's global loads (in flight across MFMA) ----
        if (more) {
            #pragma unroll
            for (int s = 0; s < 4; ++s) {
                ra0[s] = *(const float4v*)(pa[s]);
                ra1[s] = *(const float4v*)(pa[s] + 4);
                rb0[s] = *(const float4v*)(pb[s]);
                rb1[s] = *(const float4v*)(pb[s] + 4);
                pa[s] += BK; pb[s] += BK;
            }
        }

        // ---- MFMA phase over lds[cur] ----
        #pragma unroll
        for (int ks = 0; ks < 4; ++ks) {
            const int cp = 2 * ks + kg;                    // k-chunk 0..7
            const int pa0 = ((wm      + ml) * 8 + (cp ^ sw)) * 8;
            const int pa1 = ((wm + 32 + ml) * 8 + (cp ^ sw)) * 8;
            const int pb0 = ((wn      + ml) * 8 + (cp ^ sw)) * 8;
            const int pb1 = ((wn + 32 + ml) * 8 + (cp ^ sw)) * 8;
            half8 a0 = *(const half8*)&sA[cur][pa0];
            half8 a1 = *(const half8*)&sA[cur][pa1];
            half8 b0 = *(const half8*)&sB[cur][pb0];
            half8 b1 = *(const half8*)&sB[cur][pb1];
            acc[0][0] = __builtin_amdgcn_mfma_f32_32x32x16_f16(a0, b0, acc[0][0], 0, 0, 0);
            acc[0][1] = __builtin_amdgcn_mfma_f32_32x32x16_f16(a0, b1, acc[0][1], 0, 0, 0);
            acc[1][0] = __builtin_amdgcn_mfma_f32_32x32x16_f16(a1, b0, acc[1][0], 0, 0, 0);
            acc[1][1] = __builtin_amdgcn_mfma_f32_32x32x16_f16(a1, b1, acc[1][1], 0, 0, 0);
        }

        // ---- cvt + write other buffer (loads drained here, after MFMA) ----
        if (more) {
            const int nxt = cur ^ 1;
            #pragma unroll
            for (int s = 0; s < 4; ++s) {
                half8 ha, hb;
                ha[0]=(half_t)ra0[s][0]; ha[1]=(half_t)ra0[s][1]; ha[2]=(half_t)ra0[s][2]; ha[3]=(half_t)ra0[s][3];
                ha[4]=(half_t)ra1[s][0]; ha[5]=(half_t)ra1[s][1]; ha[6]=(half_t)ra1[s][2]; ha[7]=(half_t)ra1[s][3];
                hb[0]=(half_t)rb0[s][0]; hb[1]=(half_t)rb0[s][1]; hb[2]=(half_t)rb0[s][2]; hb[3]=(half_t)rb0[s][3];
                hb[4]=(half_t)rb1[s][0]; hb[5]=(half_t)rb1[s][1]; hb[6]=(half_t)rb1[s][2]; hb[7]=(half_t)rb1[s][3];
                *(half8*)&sA[nxt][ldsoff[s]] = ha;
                *(half8*)&sB[nxt][ldsoff[s]] = hb;
            }
        }
        __syncthreads();
        cur ^= 1;
    }

    // Epilogue. 32x32 C/D layout [m74/m101]: col = lane&31,
    // row = (reg&3) + 8*(reg>>2) + 4*(lane>>5)
    const int cl = lane & 31;
    const int rb = 4 * (lane >> 5);
    #pragma unroll
    for (int j = 0; j < 2; ++j) {
        const int col = bn + wn + j * 32 + cl;
        const float bq = (float)(half_t)bias[col];   // inline bias quantize
        #pragma unroll
        for (int i = 0; i < 2; ++i) {
            #pragma unroll
            for (int r = 0; r < 16; ++r) {
                const int row = bm + wm + i * 32 + (r & 3) + 8 * (r >> 2) + rb;
                C[(long)row * N + col] = acc[i][j][r] + bq;
            }
        }
    }
}

extern "C" void kernel_launch(void* const* d_in, const int* in_sizes, int n_in,
                              void* d_out, int out_size, void* d_ws, size_t ws_size,
                              hipStream_t stream) {
    const float* x    = (const float*)d_in[0];
    const float* w    = (const float*)d_in[1];
    const float* bias = (const float*)d_in[2];
    float* out = (float*)d_out;

    const int OUT = in_sizes[2];
    const int IN  = in_sizes[1] / OUT;
    const int M   = in_sizes[0] / IN;
    const int N   = OUT, K = IN;

    dim3 grid((N / BN) * (M / BM));
    gemm_qf16_dbuf<<<grid, 256, 0, stream>>>(x, w, bias, out, M, N, K);
    (void)d_ws; (void)ws_size; (void)n_in; (void)out_size;
}